// Round 2
// baseline (341.356 us; speedup 1.0000x reference)
//
#include <hip/hip_runtime.h>
#include <hip/hip_bf16.h>
#include <cmath>

// FeedForwardQuantum: out = relu(cumprod(cos(x[...,:8])) @ w1^T + b1) @ w2^T + b2
// B=4 T=4096 C=1024 F=4096 -> M=16384 tokens, dominant GEMM [M,4096]x[4096,1024].

typedef __attribute__((ext_vector_type(8))) __bf16 bf16x8;
typedef __attribute__((ext_vector_type(4))) float f32x4;
typedef __attribute__((ext_vector_type(8))) unsigned short ushortx8;

#define GAS __attribute__((address_space(1)))
#define LAS __attribute__((address_space(3)))

__device__ __forceinline__ unsigned short f32_to_bf16(float f) {
    union { float f; unsigned int u; } v; v.f = f;
    unsigned int u = v.u;
    u += 0x7FFFu + ((u >> 16) & 1u);   // round-to-nearest-even
    return (unsigned short)(u >> 16);
}

// ---------------- kernel 1: w2 fp32 -> bf16 ----------------
__global__ __launch_bounds__(256) void cvt_w2(const float* __restrict__ src,
                                              unsigned short* __restrict__ dst) {
    int i = blockIdx.x * 256 + threadIdx.x;       // 8 elements per thread
    const float4* s = reinterpret_cast<const float4*>(src);
    float4 a = s[2 * i], b = s[2 * i + 1];
    ushortx8 o;
    o[0] = f32_to_bf16(a.x); o[1] = f32_to_bf16(a.y);
    o[2] = f32_to_bf16(a.z); o[3] = f32_to_bf16(a.w);
    o[4] = f32_to_bf16(b.x); o[5] = f32_to_bf16(b.y);
    o[6] = f32_to_bf16(b.z); o[7] = f32_to_bf16(b.w);
    reinterpret_cast<ushortx8*>(dst)[i] = o;
}

// ---------------- kernel 2: H = relu(q @ w1^T + b1) in bf16 ----------------
// q[t,j] = prod_{k<=j} cos(x[t,k]).  8 tokens per block, 256 threads.
__global__ __launch_bounds__(256) void h_kernel(const float* __restrict__ x,
                                                const float* __restrict__ w1,
                                                const float* __restrict__ b1,
                                                unsigned short* __restrict__ H) {
    constexpr int C = 1024, F = 4096;
    __shared__ float qs[8][8];
    const int tid = threadIdx.x;
    const int t0 = blockIdx.x * 8;

    if (tid < 8) {
        const float* xr = x + (size_t)(t0 + tid) * C;
        float p = 1.0f;
        #pragma unroll
        for (int j = 0; j < 8; ++j) { p *= cosf(xr[j]); qs[tid][j] = p; }
    }
    __syncthreads();

    float q[8][8];
    #pragma unroll
    for (int tt = 0; tt < 8; ++tt)
        #pragma unroll
        for (int j = 0; j < 8; ++j) q[tt][j] = qs[tt][j];

    #pragma unroll
    for (int i = 0; i < 2; ++i) {
        const int f0 = (i * 256 + tid) * 8;      // 8 consecutive f's
        float s[8][8];                           // [token][f]
        #pragma unroll
        for (int u = 0; u < 8; ++u) {
            const float4* wp = reinterpret_cast<const float4*>(w1 + (size_t)(f0 + u) * 8);
            float4 wa = wp[0], wb = wp[1];
            float w8[8] = {wa.x, wa.y, wa.z, wa.w, wb.x, wb.y, wb.z, wb.w};
            float bb = b1[f0 + u];
            #pragma unroll
            for (int tt = 0; tt < 8; ++tt) {
                float acc = bb;
                #pragma unroll
                for (int j = 0; j < 8; ++j) acc += q[tt][j] * w8[j];
                s[tt][u] = fmaxf(acc, 0.0f);
            }
        }
        #pragma unroll
        for (int tt = 0; tt < 8; ++tt) {
            ushortx8 o;
            #pragma unroll
            for (int u = 0; u < 8; ++u) o[u] = f32_to_bf16(s[tt][u]);
            *reinterpret_cast<ushortx8*>(H + (size_t)(t0 + tt) * F + f0) = o;
        }
    }
}

// ---------------- kernel 3: C[M,N] = A[M,K] * B[N,K]^T + bias ----------------
// m97 structure: 128x128 tile, BK=32, 4 waves, global_load_lds width 16,
// mfma_f32_16x16x32_bf16, acc 4x4 fragments per wave (64x64 per wave).
__global__ __launch_bounds__(256) void gemm_bt(const unsigned short* __restrict__ A,
                                               const unsigned short* __restrict__ B,
                                               const float* __restrict__ bias,
                                               float* __restrict__ C) {
    constexpr int M = 16384, N = 1024, K = 4096;
    constexpr int BM = 128, BN = 128, BK = 32;
    constexpr int NWG = (M / BM) * (N / BN);   // 1024, % 8 == 0
    constexpr int CPX = NWG / 8;

    __shared__ unsigned short As[BM * BK];     // 8 KB, linear row-major [128][32]
    __shared__ unsigned short Bs[BN * BK];     // 8 KB

    const int tid  = threadIdx.x;
    const int wave = tid >> 6;
    const int lane = tid & 63;

    // XCD-aware bijective swizzle (NWG % 8 == 0)
    const int bid = blockIdx.x;
    const int wg  = (bid & 7) * CPX + (bid >> 3);
    const int tm  = wg >> 3;                    // N/BN = 8 tiles in N
    const int tn  = wg & 7;
    const int rowBase = tm * BM;
    const int colBase = tn * BN;

    const int wr = wave >> 1;                   // wave 64x64 sub-tile
    const int wc = wave & 1;

    f32x4 acc[4][4];
    #pragma unroll
    for (int m = 0; m < 4; ++m)
        #pragma unroll
        for (int n = 0; n < 4; ++n) acc[m][n] = (f32x4){0.f, 0.f, 0.f, 0.f};

    const int rl = lane & 15;
    const int kq = lane >> 4;
    const int kcol = kq * 8;

    for (int k0 = 0; k0 < K; k0 += BK) {
        // ---- stage A,B tiles: 2 issues x 256 threads x 16B each ----
        #pragma unroll
        for (int i = 0; i < 2; ++i) {
            const int e = (i * 256 + tid) * 8;  // element offset in 128x32 tile
            const int r = e >> 5;
            const int c = e & 31;
            const unsigned short* ga = A + (size_t)(rowBase + r) * K + k0 + c;
            const unsigned short* gb = B + (size_t)(colBase + r) * K + k0 + c;
            __builtin_amdgcn_global_load_lds((const GAS unsigned int*)(const void*)ga,
                                             (LAS unsigned int*)(void*)(As + e), 16, 0, 0);
            __builtin_amdgcn_global_load_lds((const GAS unsigned int*)(const void*)gb,
                                             (LAS unsigned int*)(void*)(Bs + e), 16, 0, 0);
        }
        __syncthreads();   // drains vmcnt before any wave reads LDS

        bf16x8 af[4], bf[4];
        #pragma unroll
        for (int m = 0; m < 4; ++m)
            af[m] = *reinterpret_cast<const bf16x8*>(As + (wr * 64 + m * 16 + rl) * BK + kcol);
        #pragma unroll
        for (int n = 0; n < 4; ++n)
            bf[n] = *reinterpret_cast<const bf16x8*>(Bs + (wc * 64 + n * 16 + rl) * BK + kcol);

        #pragma unroll
        for (int m = 0; m < 4; ++m)
            #pragma unroll
            for (int n = 0; n < 4; ++n)
                acc[m][n] = __builtin_amdgcn_mfma_f32_16x16x32_bf16(af[m], bf[n], acc[m][n], 0, 0, 0);

        __syncthreads();   // protect LDS before next stage overwrites
    }

    // ---- epilogue: C/D layout col=lane&15, row=(lane>>4)*4+reg ----
    const int rq = lane >> 4;
    #pragma unroll
    for (int n = 0; n < 4; ++n) {
        const int col = colBase + wc * 64 + n * 16 + rl;
        const float bv = bias[col];
        #pragma unroll
        for (int m = 0; m < 4; ++m) {
            #pragma unroll
            for (int j = 0; j < 4; ++j) {
                const int row = rowBase + wr * 64 + m * 16 + rq * 4 + j;
                C[(size_t)row * N + col] = acc[m][n][j] + bv;
            }
        }
    }
}

extern "C" void kernel_launch(void* const* d_in, const int* in_sizes, int n_in,
                              void* d_out, int out_size, void* d_ws, size_t ws_size,
                              hipStream_t stream) {
    const float* x  = (const float*)d_in[0];
    // d_in[1] = circuit_params: provably cancels (x 0.0) in the reference
    const float* w1 = (const float*)d_in[2];
    const float* b1 = (const float*)d_in[3];
    const float* w2 = (const float*)d_in[4];
    const float* b2 = (const float*)d_in[5];
    float* out = (float*)d_out;

    constexpr int M = 16384;   // B*T tokens
    constexpr int N = 1024;    // embed dim C
    constexpr int K = 4096;    // ffn dim F

    unsigned short* Hbuf = (unsigned short*)d_ws;                              // M*K bf16 = 128 MB
    unsigned short* w2bf = (unsigned short*)((char*)d_ws + (size_t)M * K * 2); // N*K bf16 = 8 MB

    cvt_w2<<<(N * K) / (256 * 8), 256, 0, stream>>>(w2, w2bf);
    h_kernel<<<M / 8, 256, 0, stream>>>(x, w1, b1, Hbuf);
    gemm_bt<<<(M / 128) * (N / 128), 256, 0, stream>>>(Hbuf, w2bf, b2, out);
}

// Round 3
// 261.796 us; speedup vs baseline: 1.3039x; 1.3039x over previous
//
#include <hip/hip_runtime.h>
#include <hip/hip_bf16.h>
#include <cmath>

// FeedForwardQuantum: out = relu(cumprod(cos(x[...,:8])) @ w1^T + b1) @ w2^T + b2
// B=4 T=4096 C=1024 F=4096 -> M=16384 tokens, dominant GEMM [M,4096]x[4096,1024]^T.

typedef __attribute__((ext_vector_type(8))) __bf16 bf16x8;
typedef __attribute__((ext_vector_type(4))) float f32x4;
typedef __attribute__((ext_vector_type(8))) unsigned short ushortx8;

#define GAS __attribute__((address_space(1)))
#define LAS __attribute__((address_space(3)))

__device__ __forceinline__ unsigned short f32_to_bf16(float f) {
    union { float f; unsigned int u; } v; v.f = f;
    unsigned int u = v.u;
    u += 0x7FFFu + ((u >> 16) & 1u);   // round-to-nearest-even
    return (unsigned short)(u >> 16);
}

// ---------------- kernel 1: w2 fp32 -> bf16 ----------------
__global__ __launch_bounds__(256) void cvt_w2(const float* __restrict__ src,
                                              unsigned short* __restrict__ dst) {
    int i = blockIdx.x * 256 + threadIdx.x;       // 8 elements per thread
    const float4* s = reinterpret_cast<const float4*>(src);
    float4 a = s[2 * i], b = s[2 * i + 1];
    ushortx8 o;
    o[0] = f32_to_bf16(a.x); o[1] = f32_to_bf16(a.y);
    o[2] = f32_to_bf16(a.z); o[3] = f32_to_bf16(a.w);
    o[4] = f32_to_bf16(b.x); o[5] = f32_to_bf16(b.y);
    o[6] = f32_to_bf16(b.z); o[7] = f32_to_bf16(b.w);
    reinterpret_cast<ushortx8*>(dst)[i] = o;
}

// ---------------- kernel 2: H = relu(q @ w1^T + b1) in bf16 ----------------
// Rewritten: thread owns 8 consecutive f's (w1 in 64 regs), loops 32 tokens.
// Fixes round-2 scratch-spill (q[8][8]+s[8][8]+w 64 -> 140+ live floats).
__global__ __launch_bounds__(256) void h_kernel(const float* __restrict__ x,
                                                const float* __restrict__ w1,
                                                const float* __restrict__ b1,
                                                unsigned short* __restrict__ H) {
    constexpr int C = 1024, F = 4096, TOK = 32;
    __shared__ float qs[TOK][8];
    const int tid = threadIdx.x;
    const int tb  = blockIdx.x & 511;   // 512 token blocks
    const int fb  = blockIdx.x >> 9;    // 2 f blocks
    const int t0  = tb * TOK;
    const int f0  = fb * 2048 + tid * 8;

    if (tid < TOK) {
        const float* xr = x + (size_t)(t0 + tid) * C;
        float p = 1.0f;
        #pragma unroll
        for (int j = 0; j < 8; ++j) { p *= cosf(xr[j]); qs[tid][j] = p; }
    }

    float w[8][8]; float bb[8];
    #pragma unroll
    for (int u = 0; u < 8; ++u) {
        const float4* wp = reinterpret_cast<const float4*>(w1 + (size_t)(f0 + u) * 8);
        float4 a = wp[0], c = wp[1];
        w[u][0] = a.x; w[u][1] = a.y; w[u][2] = a.z; w[u][3] = a.w;
        w[u][4] = c.x; w[u][5] = c.y; w[u][6] = c.z; w[u][7] = c.w;
        bb[u] = b1[f0 + u];
    }
    __syncthreads();

    for (int tt = 0; tt < TOK; ++tt) {
        float q[8];
        #pragma unroll
        for (int j = 0; j < 8; ++j) q[j] = qs[tt][j];   // LDS broadcast
        ushortx8 o;
        #pragma unroll
        for (int u = 0; u < 8; ++u) {
            float acc = bb[u];
            #pragma unroll
            for (int j = 0; j < 8; ++j) acc += q[j] * w[u][j];
            o[u] = f32_to_bf16(fmaxf(acc, 0.0f));
        }
        *reinterpret_cast<ushortx8*>(H + (size_t)(t0 + tt) * F + f0) = o;
    }
}

// ---------------- kernel 3: 256x256 8-phase GEMM, C = A * B^T + bias ----------
// A[M,K]=H bf16, B[N,K]=w2 bf16, C[M,N] f32.  BM=BN=256, BK=64, 512 thr (8 waves
// 2Mx4N), 128 KiB LDS: [buf2][A/B][half2][128x64].  A-half = rows bit6, B-half =
// rows bit5 (interleaved so phases consume halves staggered).  XOR chunk swizzle
// (chunk ^= row&7) applied on global SOURCE (linear LDS dest, rule #21) and on
// ds_read addr.  Per phase: ds-reads, 1 half-tile stage (2 x gload_lds 16B),
// barrier, lgkmcnt(0), setprio(1), 16 MFMA, setprio(0), vmcnt(6), barrier.
__global__ __launch_bounds__(512, 2) void gemm256(const unsigned short* __restrict__ A,
                                                  const unsigned short* __restrict__ B,
                                                  const float* __restrict__ bias,
                                                  float* __restrict__ C) {
    constexpr int M = 16384, N = 1024, K = 4096;
    constexpr int BM = 256, BN = 256, BK = 64;
    constexpr int NKT = K / BK;                 // 64 K-tiles

    __shared__ __align__(16) unsigned short lds[2][2][2][128 * 64];  // 128 KiB

    const int tid  = threadIdx.x;
    const int wv   = tid >> 6;
    const int lane = tid & 63;
    const int wr   = wv >> 2;                   // 2 waves in M
    const int wc   = wv & 3;                    // 4 waves in N
    const int rl   = lane & 15;
    const int kq4  = lane >> 4;

    // XCD swizzle: 256 WGs, 32/XCD share one B-panel (2 MB, L2-resident)
    const int bid = blockIdx.x;
    const int wg  = (bid & 7) * 32 + (bid >> 3);
    const int tm  = wg & 63;
    const int tn  = wg >> 6;
    const int rowBase = tm * BM;
    const int colBase = tn * BN;

    // ---- staging addresses (pre-swizzled global source, linear LDS dest) ----
    const int i0 = tid >> 3;                            // row in half-tile, l=0
    const int sw = ((tid & 7) ^ (i0 & 7)) * 8;          // swizzled col chunk
    const unsigned short* pA0 = A + (size_t)(rowBase + i0) * K + sw;
    const unsigned short* pA1 = A + (size_t)(rowBase + i0 + 128) * K + sw;
    const int bR0 = (i0 & 31) + ((i0 >> 5) << 6);
    const unsigned short* pB0 = B + (size_t)(colBase + bR0) * K + sw;
    const unsigned short* pB1 = B + (size_t)(colBase + bR0 + 128) * K + sw;

#define STAGE_A(HH, BB, KT)  do {                                                   \
    __builtin_amdgcn_global_load_lds((const GAS unsigned int*)(const void*)          \
        (pA0 + (size_t)(HH) * 64 * K + (KT) * 64),                                   \
        (LAS unsigned int*)(void*)&lds[BB][0][HH][tid * 8], 16, 0, 0);               \
    __builtin_amdgcn_global_load_lds((const GAS unsigned int*)(const void*)          \
        (pA1 + (size_t)(HH) * 64 * K + (KT) * 64),                                   \
        (LAS unsigned int*)(void*)&lds[BB][0][HH][4096 + tid * 8], 16, 0, 0);        \
} while (0)
#define STAGE_B(HH, BB, KT)  do {                                                   \
    __builtin_amdgcn_global_load_lds((const GAS unsigned int*)(const void*)          \
        (pB0 + (size_t)(HH) * 32 * K + (KT) * 64),                                   \
        (LAS unsigned int*)(void*)&lds[BB][1][HH][tid * 8], 16, 0, 0);               \
    __builtin_amdgcn_global_load_lds((const GAS unsigned int*)(const void*)          \
        (pB1 + (size_t)(HH) * 32 * K + (KT) * 64),                                   \
        (LAS unsigned int*)(void*)&lds[BB][1][HH][4096 + tid * 8], 16, 0, 0);        \
} while (0)

    // ---- ds_read offsets (elements) ----
    const int ch0  = ((0 + kq4) ^ (rl & 7)) * 8;        // k-half 0 chunk
    const int ch1  = ((4 + kq4) ^ (rl & 7)) * 8;        // k-half 1 chunk
    const int aOff = (wr * 64 + rl) * 64;
    const int bOff = (wc * 32 + rl) * 64;

    bf16x8 aF[4][2], bF0[2][2], bF1[2][2];
    f32x4 acc[8][4];
    #pragma unroll
    for (int m = 0; m < 8; ++m)
        #pragma unroll
        for (int n = 0; n < 4; ++n) acc[m][n] = (f32x4){0.f, 0.f, 0.f, 0.f};

#define LOAD_A(HH) { _Pragma("unroll")                                               \
    for (int m_ = 0; m_ < 4; ++m_) {                                                 \
        aF[m_][0] = *(const bf16x8*)&lds[b][0][HH][aOff + m_ * 1024 + ch0];          \
        aF[m_][1] = *(const bf16x8*)&lds[b][0][HH][aOff + m_ * 1024 + ch1]; } }
#define LOAD_B(DST, HH) { _Pragma("unroll")                                          \
    for (int n_ = 0; n_ < 2; ++n_) {                                                 \
        DST[n_][0] = *(const bf16x8*)&lds[b][1][HH][bOff + n_ * 1024 + ch0];         \
        DST[n_][1] = *(const bf16x8*)&lds[b][1][HH][bOff + n_ * 1024 + ch1]; } }
#define MFMA_QUAD(BF, MO, NO) { _Pragma("unroll")                                    \
    for (int m_ = 0; m_ < 4; ++m_) { _Pragma("unroll")                               \
        for (int n_ = 0; n_ < 2; ++n_) {                                             \
            acc[MO + m_][NO + n_] = __builtin_amdgcn_mfma_f32_16x16x32_bf16(         \
                aF[m_][0], BF[n_][0], acc[MO + m_][NO + n_], 0, 0, 0);               \
            acc[MO + m_][NO + n_] = __builtin_amdgcn_mfma_f32_16x16x32_bf16(         \
                aF[m_][1], BF[n_][1], acc[MO + m_][NO + n_], 0, 0, 0); } } }
#define PHASE_TAIL(MFMAS) do {                                                       \
    __builtin_amdgcn_s_barrier();                                                    \
    asm volatile("s_waitcnt lgkmcnt(0)" ::: "memory");                               \
    __builtin_amdgcn_sched_barrier(0);                                               \
    __builtin_amdgcn_s_setprio(1);                                                   \
    MFMAS                                                                            \
    __builtin_amdgcn_s_setprio(0);                                                   \
    __builtin_amdgcn_sched_barrier(0);                                               \
    asm volatile("s_waitcnt vmcnt(6)" ::: "memory");                                 \
    __builtin_amdgcn_s_barrier();                                                    \
    __builtin_amdgcn_sched_barrier(0);                                               \
} while (0)

    // ---- prologue: 6 half-tiles in steady-state aging order ----
    STAGE_A(0, 0, 0);   // A-h0(kt0)
    STAGE_B(1, 0, 0);   // B-h1(kt0)
    STAGE_B(0, 0, 0);   // B-h0(kt0)
    STAGE_A(1, 0, 0);   // A-h1(kt0)
    STAGE_A(0, 1, 1);   // A-h0(kt1)
    STAGE_B(1, 1, 1);   // B-h1(kt1)
    asm volatile("s_waitcnt vmcnt(6)" ::: "memory");    // kt0: A-h0,B-h1,B-h0 landed
    __builtin_amdgcn_s_barrier();
    __builtin_amdgcn_sched_barrier(0);

    #pragma unroll 2
    for (int kt = 0; kt < NKT; ++kt) {
        const int b = kt & 1;
        // -- Phase 0: quadrant (mh0, nh0) --
        LOAD_A(0); LOAD_B(bF0, 0);
        if (kt < NKT - 1) STAGE_B(0, b ^ 1, kt + 1);
        PHASE_TAIL(MFMA_QUAD(bF0, 0, 0));
        // -- Phase 1: quadrant (mh0, nh1) --
        LOAD_B(bF1, 1);
        if (kt < NKT - 1) STAGE_A(1, b ^ 1, kt + 1);
        PHASE_TAIL(MFMA_QUAD(bF1, 0, 2));
        // -- Phase 2: quadrant (mh1, nh1) --
        LOAD_A(1);
        if (kt < NKT - 2) STAGE_A(0, b, kt + 2);
        PHASE_TAIL(MFMA_QUAD(bF1, 4, 2));
        // -- Phase 3: quadrant (mh1, nh0) --
        if (kt < NKT - 2) STAGE_B(1, b, kt + 2);
        PHASE_TAIL(MFMA_QUAD(bF0, 4, 0));
    }

    // ---- epilogue: C/D layout col=lane&15, row=(lane>>4)*4+j ----
    const int rq = lane >> 4;
    #pragma unroll
    for (int n = 0; n < 4; ++n) {
        const int col = colBase + wc * 64 + n * 16 + rl;
        const float bv = bias[col];
        #pragma unroll
        for (int m = 0; m < 8; ++m) {
            #pragma unroll
            for (int j = 0; j < 4; ++j) {
                const int row = rowBase + wr * 128 + m * 16 + rq * 4 + j;
                C[(size_t)row * N + col] = acc[m][n][j] + bv;
            }
        }
    }
#undef STAGE_A
#undef STAGE_B
#undef LOAD_A
#undef LOAD_B
#undef MFMA_QUAD
#undef PHASE_TAIL
}

extern "C" void kernel_launch(void* const* d_in, const int* in_sizes, int n_in,
                              void* d_out, int out_size, void* d_ws, size_t ws_size,
                              hipStream_t stream) {
    const float* x  = (const float*)d_in[0];
    // d_in[1] = circuit_params: provably cancels (x 0.0) in the reference
    const float* w1 = (const float*)d_in[2];
    const float* b1 = (const float*)d_in[3];
    const float* w2 = (const float*)d_in[4];
    const float* b2 = (const float*)d_in[5];
    float* out = (float*)d_out;

    constexpr int M = 16384;   // B*T tokens
    constexpr int N = 1024;    // embed dim C
    constexpr int K = 4096;    // ffn dim F

    unsigned short* Hbuf = (unsigned short*)d_ws;                              // 128 MB
    unsigned short* w2bf = (unsigned short*)((char*)d_ws + (size_t)M * K * 2); // 8 MB

    cvt_w2<<<(N * K) / (256 * 8), 256, 0, stream>>>(w2, w2bf);
    h_kernel<<<(M / 32) * 2, 256, 0, stream>>>(x, w1, b1, Hbuf);
    gemm256<<<(M / 256) * (N / 256), 512, 0, stream>>>(Hbuf, w2bf, b2, out);
}

// Round 4
// 254.358 us; speedup vs baseline: 1.3420x; 1.0292x over previous
//
#include <hip/hip_runtime.h>
#include <hip/hip_bf16.h>
#include <cmath>

// FeedForwardQuantum: out = relu(cumprod(cos(x[...,:8])) @ w1^T + b1) @ w2^T + b2
// B=4 T=4096 C=1024 F=4096 -> M=16384 tokens, dominant GEMM [M,4096]x[4096,1024]^T.

typedef __attribute__((ext_vector_type(8))) __bf16 bf16x8;
typedef __attribute__((ext_vector_type(4))) float f32x4;
typedef __attribute__((ext_vector_type(8))) unsigned short ushortx8;

#define GAS __attribute__((address_space(1)))
#define LAS __attribute__((address_space(3)))

__device__ __forceinline__ unsigned short f32_to_bf16(float f) {
    union { float f; unsigned int u; } v; v.f = f;
    unsigned int u = v.u;
    u += 0x7FFFu + ((u >> 16) & 1u);   // round-to-nearest-even
    return (unsigned short)(u >> 16);
}

// ---------------- kernel 1: fused H-compute + w2 conversion ----------------
// blocks [0,1024): H = relu(q @ w1^T + b1) bf16, thread owns 8 f's, 32 tokens.
// blocks [1024,3072): w2 fp32 -> bf16 (8 elems/thread).
__global__ __launch_bounds__(256) void h_cvt_kernel(const float* __restrict__ x,
                                                    const float* __restrict__ w1,
                                                    const float* __restrict__ b1,
                                                    const float* __restrict__ w2,
                                                    unsigned short* __restrict__ H,
                                                    unsigned short* __restrict__ w2bf) {
    constexpr int C = 1024, F = 4096, TOK = 32;
    const int tid = threadIdx.x;
    const int bid = blockIdx.x;

    if (bid >= 1024) {                // ---- w2 conversion branch ----
        int i = (bid - 1024) * 256 + tid;
        const float4* s = reinterpret_cast<const float4*>(w2);
        float4 a = s[2 * i], b = s[2 * i + 1];
        ushortx8 o;
        o[0] = f32_to_bf16(a.x); o[1] = f32_to_bf16(a.y);
        o[2] = f32_to_bf16(a.z); o[3] = f32_to_bf16(a.w);
        o[4] = f32_to_bf16(b.x); o[5] = f32_to_bf16(b.y);
        o[6] = f32_to_bf16(b.z); o[7] = f32_to_bf16(b.w);
        reinterpret_cast<ushortx8*>(w2bf)[i] = o;
        return;
    }

    // ---- H branch ----
    __shared__ float qs[TOK][8];
    const int tb = bid & 511;          // 512 token blocks
    const int fb = bid >> 9;           // 2 f blocks
    const int t0 = tb * TOK;
    const int f0 = fb * 2048 + tid * 8;

    if (tid < TOK) {
        const float* xr = x + (size_t)(t0 + tid) * C;
        float p = 1.0f;
        #pragma unroll
        for (int j = 0; j < 8; ++j) { p *= cosf(xr[j]); qs[tid][j] = p; }
    }

    float w[8][8]; float bb[8];
    #pragma unroll
    for (int u = 0; u < 8; ++u) {
        const float4* wp = reinterpret_cast<const float4*>(w1 + (size_t)(f0 + u) * 8);
        float4 a = wp[0], c = wp[1];
        w[u][0] = a.x; w[u][1] = a.y; w[u][2] = a.z; w[u][3] = a.w;
        w[u][4] = c.x; w[u][5] = c.y; w[u][6] = c.z; w[u][7] = c.w;
        bb[u] = b1[f0 + u];
    }
    __syncthreads();

    for (int tt = 0; tt < TOK; ++tt) {
        float q[8];
        #pragma unroll
        for (int j = 0; j < 8; ++j) q[j] = qs[tt][j];   // LDS broadcast
        ushortx8 o;
        #pragma unroll
        for (int u = 0; u < 8; ++u) {
            float acc = bb[u];
            #pragma unroll
            for (int j = 0; j < 8; ++j) acc += q[j] * w[u][j];
            o[u] = f32_to_bf16(fmaxf(acc, 0.0f));
        }
        *reinterpret_cast<ushortx8*>(H + (size_t)(t0 + tt) * F + f0) = o;
    }
}

// ---------------- kernel 2: 256x256 8-phase GEMM, C = A * B^T + bias ----------
// A[M,K]=H bf16, B[N,K]=w2 bf16, C[M,N] f32.  BM=BN=256, BK=64, 512 thr (8 waves
// 2Mx4N), 128 KiB LDS: [buf2][A/B][half2][128x64].  XOR chunk swizzle on global
// SOURCE (linear LDS dest) and on ds_read addr.  Per phase: ds-reads, 1 half-tile
// stage, barrier, lgkmcnt(0), setprio(1), 16 MFMA, setprio(0), vmcnt(6), barrier.
// Round-4: XCD-local A-panel sharing — the 4 WGs with equal tm sit on ONE XCD.
__global__ __launch_bounds__(512, 2) void gemm256(const unsigned short* __restrict__ A,
                                                  const unsigned short* __restrict__ B,
                                                  const float* __restrict__ bias,
                                                  float* __restrict__ C) {
    constexpr int M = 16384, N = 1024, K = 4096;
    constexpr int BM = 256, BN = 256, BK = 64;
    constexpr int NKT = K / BK;                 // 64 K-tiles

    __shared__ __align__(16) unsigned short lds[2][2][2][128 * 64];  // 128 KiB

    const int tid  = threadIdx.x;
    const int wv   = tid >> 6;
    const int lane = tid & 63;
    const int wr   = wv >> 2;                   // 2 waves in M
    const int wc   = wv & 3;                    // 4 waves in N
    const int rl   = lane & 15;
    const int kq4  = lane >> 4;

    // XCD-local swizzle: XCD x owns tm in [x*8, x*8+8) x all 4 tn.
    // Same-tm WGs are co-resident on one XCD -> A-panel fetched once into its L2.
    const int bid = blockIdx.x;
    const int xcd = bid & 7;
    const int loc = bid >> 3;                   // 0..31
    const int tm  = xcd * 8 + (loc & 7);        // 0..63
    const int tn  = loc >> 3;                   // 0..3
    const int rowBase = tm * BM;
    const int colBase = tn * BN;

    // ---- staging addresses (pre-swizzled global source, linear LDS dest) ----
    const int i0 = tid >> 3;                            // row in half-tile, l=0
    const int sw = ((tid & 7) ^ (i0 & 7)) * 8;          // swizzled col chunk
    const unsigned short* pA0 = A + (size_t)(rowBase + i0) * K + sw;
    const unsigned short* pA1 = A + (size_t)(rowBase + i0 + 128) * K + sw;
    const int bR0 = (i0 & 31) + ((i0 >> 5) << 6);
    const unsigned short* pB0 = B + (size_t)(colBase + bR0) * K + sw;
    const unsigned short* pB1 = B + (size_t)(colBase + bR0 + 128) * K + sw;

#define STAGE_A(HH, BB, KT)  do {                                                   \
    __builtin_amdgcn_global_load_lds((const GAS unsigned int*)(const void*)          \
        (pA0 + (size_t)(HH) * 64 * K + (KT) * 64),                                   \
        (LAS unsigned int*)(void*)&lds[BB][0][HH][tid * 8], 16, 0, 0);               \
    __builtin_amdgcn_global_load_lds((const GAS unsigned int*)(const void*)          \
        (pA1 + (size_t)(HH) * 64 * K + (KT) * 64),                                   \
        (LAS unsigned int*)(void*)&lds[BB][0][HH][4096 + tid * 8], 16, 0, 0);        \
} while (0)
#define STAGE_B(HH, BB, KT)  do {                                                   \
    __builtin_amdgcn_global_load_lds((const GAS unsigned int*)(const void*)          \
        (pB0 + (size_t)(HH) * 32 * K + (KT) * 64),                                   \
        (LAS unsigned int*)(void*)&lds[BB][1][HH][tid * 8], 16, 0, 0);               \
    __builtin_amdgcn_global_load_lds((const GAS unsigned int*)(const void*)          \
        (pB1 + (size_t)(HH) * 32 * K + (KT) * 64),                                   \
        (LAS unsigned int*)(void*)&lds[BB][1][HH][4096 + tid * 8], 16, 0, 0);        \
} while (0)

    // ---- ds_read offsets (elements) ----
    const int ch0  = ((0 + kq4) ^ (rl & 7)) * 8;        // k-half 0 chunk
    const int ch1  = ((4 + kq4) ^ (rl & 7)) * 8;        // k-half 1 chunk
    const int aOff = (wr * 64 + rl) * 64;
    const int bOff = (wc * 32 + rl) * 64;

    bf16x8 aF[4][2], bF0[2][2], bF1[2][2];
    f32x4 acc[8][4];
    #pragma unroll
    for (int m = 0; m < 8; ++m)
        #pragma unroll
        for (int n = 0; n < 4; ++n) acc[m][n] = (f32x4){0.f, 0.f, 0.f, 0.f};

#define LOAD_A(HH) { _Pragma("unroll")                                               \
    for (int m_ = 0; m_ < 4; ++m_) {                                                 \
        aF[m_][0] = *(const bf16x8*)&lds[b][0][HH][aOff + m_ * 1024 + ch0];          \
        aF[m_][1] = *(const bf16x8*)&lds[b][0][HH][aOff + m_ * 1024 + ch1]; } }
#define LOAD_B(DST, HH) { _Pragma("unroll")                                          \
    for (int n_ = 0; n_ < 2; ++n_) {                                                 \
        DST[n_][0] = *(const bf16x8*)&lds[b][1][HH][bOff + n_ * 1024 + ch0];         \
        DST[n_][1] = *(const bf16x8*)&lds[b][1][HH][bOff + n_ * 1024 + ch1]; } }
#define MFMA_QUAD(BF, MO, NO) { _Pragma("unroll")                                    \
    for (int m_ = 0; m_ < 4; ++m_) { _Pragma("unroll")                               \
        for (int n_ = 0; n_ < 2; ++n_) {                                             \
            acc[MO + m_][NO + n_] = __builtin_amdgcn_mfma_f32_16x16x32_bf16(         \
                aF[m_][0], BF[n_][0], acc[MO + m_][NO + n_], 0, 0, 0);               \
            acc[MO + m_][NO + n_] = __builtin_amdgcn_mfma_f32_16x16x32_bf16(         \
                aF[m_][1], BF[n_][1], acc[MO + m_][NO + n_], 0, 0, 0); } } }
#define PHASE_TAIL(MFMAS) do {                                                       \
    __builtin_amdgcn_s_barrier();                                                    \
    asm volatile("s_waitcnt lgkmcnt(0)" ::: "memory");                               \
    __builtin_amdgcn_sched_barrier(0);                                               \
    __builtin_amdgcn_s_setprio(1);                                                   \
    MFMAS                                                                            \
    __builtin_amdgcn_s_setprio(0);                                                   \
    __builtin_amdgcn_sched_barrier(0);                                               \
    asm volatile("s_waitcnt vmcnt(6)" ::: "memory");                                 \
    __builtin_amdgcn_s_barrier();                                                    \
    __builtin_amdgcn_sched_barrier(0);                                               \
} while (0)

    // ---- prologue: 6 half-tiles in steady-state aging order ----
    STAGE_A(0, 0, 0);   // A-h0(kt0)
    STAGE_B(1, 0, 0);   // B-h1(kt0)
    STAGE_B(0, 0, 0);   // B-h0(kt0)
    STAGE_A(1, 0, 0);   // A-h1(kt0)
    STAGE_A(0, 1, 1);   // A-h0(kt1)
    STAGE_B(1, 1, 1);   // B-h1(kt1)
    asm volatile("s_waitcnt vmcnt(6)" ::: "memory");    // kt0: A-h0,B-h1,B-h0 landed
    __builtin_amdgcn_s_barrier();
    __builtin_amdgcn_sched_barrier(0);

    #pragma unroll 2
    for (int kt = 0; kt < NKT; ++kt) {
        const int b = kt & 1;
        // -- Phase 0: quadrant (mh0, nh0) --
        LOAD_A(0); LOAD_B(bF0, 0);
        if (kt < NKT - 1) STAGE_B(0, b ^ 1, kt + 1);
        PHASE_TAIL(MFMA_QUAD(bF0, 0, 0));
        // -- Phase 1: quadrant (mh0, nh1) --
        LOAD_B(bF1, 1);
        if (kt < NKT - 1) STAGE_A(1, b ^ 1, kt + 1);
        PHASE_TAIL(MFMA_QUAD(bF1, 0, 2));
        // -- Phase 2: quadrant (mh1, nh1) --
        LOAD_A(1);
        if (kt < NKT - 2) STAGE_A(0, b, kt + 2);
        PHASE_TAIL(MFMA_QUAD(bF1, 4, 2));
        // -- Phase 3: quadrant (mh1, nh0) --
        if (kt < NKT - 2) STAGE_B(1, b, kt + 2);
        PHASE_TAIL(MFMA_QUAD(bF0, 4, 0));
    }

    // ---- epilogue: C/D layout col=lane&15, row=(lane>>4)*4+j ----
    const int rq = lane >> 4;
    #pragma unroll
    for (int n = 0; n < 4; ++n) {
        const int col = colBase + wc * 64 + n * 16 + rl;
        const float bv = bias[col];
        #pragma unroll
        for (int m = 0; m < 8; ++m) {
            #pragma unroll
            for (int j = 0; j < 4; ++j) {
                const int row = rowBase + wr * 128 + m * 16 + rq * 4 + j;
                C[(size_t)row * N + col] = acc[m][n][j] + bv;
            }
        }
    }
#undef STAGE_A
#undef STAGE_B
#undef LOAD_A
#undef LOAD_B
#undef MFMA_QUAD
#undef PHASE_TAIL
}

extern "C" void kernel_launch(void* const* d_in, const int* in_sizes, int n_in,
                              void* d_out, int out_size, void* d_ws, size_t ws_size,
                              hipStream_t stream) {
    const float* x  = (const float*)d_in[0];
    // d_in[1] = circuit_params: provably cancels (x 0.0) in the reference
    const float* w1 = (const float*)d_in[2];
    const float* b1 = (const float*)d_in[3];
    const float* w2 = (const float*)d_in[4];
    const float* b2 = (const float*)d_in[5];
    float* out = (float*)d_out;

    constexpr int M = 16384;   // B*T tokens
    constexpr int N = 1024;    // embed dim C
    constexpr int K = 4096;    // ffn dim F

    unsigned short* Hbuf = (unsigned short*)d_ws;                              // 128 MB
    unsigned short* w2bf = (unsigned short*)((char*)d_ws + (size_t)M * K * 2); // 8 MB

    // blocks [0,1024): H;  [1024,3072): w2->bf16
    h_cvt_kernel<<<3072, 256, 0, stream>>>(x, w1, b1, w2, Hbuf, w2bf);
    gemm256<<<(M / 256) * (N / 256), 512, 0, stream>>>(Hbuf, w2bf, b2, out);
}